// Round 2
// baseline (569.446 us; speedup 1.0000x reference)
//
#include <hip/hip_runtime.h>

// Fused 24-step LSTM forecaster, MI355X gfx950 — round 2: VALU-issue diet.
//  * Weight LDS copy eliminated: kb/kc B-frags streamed from global every
//    step (same 16KB addresses -> L1-resident; VMEM issue, not VALU).
//    LDS = 5KB (h transpose tile only), no __syncthreads anywhere.
//  * All bf16 conversion via v_cvt_pk_bf16_f32 (1 instr / 2 values).
//  * Gate columns PERMUTED in the weight builder so a lane's two h outputs
//    are adjacent hidden indices -> h store = 4x ds_write_b32.
//  * g-gate weights pre-scaled by 2*log2e; all activations on native
//    v_exp_f32; reciprocals PAIRED (1 v_rcp per 2 activations).

#define BN     512
#define HISTN  24
#define CNN    184
#define FN     17
#define PREDN  24
#define HIDN   32
#define INN    41
#define CELLS  (BN * CNN)          // 94208 cells, 64/block -> 1472 blocks
#define FROW   (CNN * FN)
#define PMROW  (HISTN * CNN)
#define LOG2E  1.4426950408889634f

typedef __attribute__((ext_vector_type(8))) short  short8;
typedef __attribute__((ext_vector_type(4))) float  float4v;

#define MFMA_B16(a,b,c) __builtin_amdgcn_mfma_f32_16x16x32_bf16(a,b,c,0,0,0)
#define X2(x) __builtin_amdgcn_exp2f(x)

__device__ __forceinline__ short f2bf(float f) {
  union { float f; unsigned u; } v; v.f = f;
  unsigned r = v.u + 0x7fffu + ((v.u >> 16) & 1u);   // RNE
  return (short)(r >> 16);
}
__device__ __forceinline__ int cvt_pk_bf16(float lo, float hi) {
  int r;
  asm("v_cvt_pk_bf16_f32 %0, %1, %2" : "=v"(r) : "v"(lo), "v"(hi));
  return r;
}
// ra = 1/(1+ea), rb = 1/(1+eb) with a single v_rcp.
__device__ __forceinline__ void rcp_pair(float ea, float eb, float& ra, float& rb) {
  const float s  = ea + eb;
  const float p  = fmaf(ea, eb, s) + 1.0f;   // (1+ea)(1+eb)
  const float rr = __builtin_amdgcn_rcpf(p);
  ra = fmaf(eb, rr, rr);
  rb = fmaf(ea, rr, rr);
}

// ---------------------------------------------------------------------------
// Setup: folded gate weights (fc_in absorbed, bias as constant-1 column),
// bf16, MFMA B-frag order, with PERMUTED gate columns:
//   tile nt = tau*2 + (j&1), col c0 = j>>1   (tau = gate type, j = hidden idx)
// so D-lane (nt parity pair) holds adjacent hidden indices 2*c0, 2*c0+1.
// Scale: log2(e) for i,f,o rows; 2*log2(e) for g rows (tanh's 2x folded in).
__global__ void build_weights(const float* __restrict__ W_in, const float* __restrict__ b_in,
                              const float* __restrict__ W_ih, const float* __restrict__ W_hh,
                              const float* __restrict__ b_ih, const float* __restrict__ b_hh,
                              short* __restrict__ wfrag)
{
  const int tid = blockIdx.x * 256 + threadIdx.x;
  if (tid >= 128 * 12) return;
  const int g  = tid / 12;         // source gate row 0..127 (i,f,g,o blocks)
  const int kg = tid % 12;         // k-octet 0..11
  const int k0 = kg * 8;

  float v[8];
  #pragma unroll
  for (int j = 0; j < 8; ++j) v[j] = 0.f;

  if (k0 < INN) {                  // folded fc_in region (k = 0..40)
    for (int m = 0; m < HIDN; ++m) {
      const float wih = W_ih[g * HIDN + m];
      #pragma unroll
      for (int j = 0; j < 8; ++j) {
        const int k = k0 + j;
        if (k < INN) v[j] += wih * W_in[m * INN + k];
      }
    }
  }
  if (k0 <= INN && INN < k0 + 8) { // bias column k = 41
    float bv = b_ih[g] + b_hh[g];
    for (int m = 0; m < HIDN; ++m) bv += W_ih[g * HIDN + m] * b_in[m];
    v[INN - k0] = bv;
  }
  if (k0 >= 64) {                  // W_hh region (k = 64..95)
    #pragma unroll
    for (int j = 0; j < 8; ++j) v[j] = W_hh[g * HIDN + (k0 + j - 64)];
  }

  const int tau = g >> 5;          // 0=i 1=f 2=g 3=o
  const int jj  = g & 31;
  const int nt  = tau * 2 + (jj & 1);
  const int c0  = jj >> 1;
  const int f   = kg >> 2, q = kg & 3;
  const float scale = (tau == 2) ? (2.0f * LOG2E) : LOG2E;
  short* dst = wfrag + (((f * 8 + nt) * 64 + q * 16 + c0) * 8);
  #pragma unroll
  for (int j = 0; j < 8; ++j) dst[j] = f2bf(v[j] * scale);
}

// ---------------------------------------------------------------------------
__global__ __launch_bounds__(256, 4)
void lstm_fused(const float* __restrict__ pm25,
                const float* __restrict__ feat,
                const short* __restrict__ wfrag,
                const float* __restrict__ W_out, const float* __restrict__ b_out,
                float* __restrict__ out)
{
  __shared__ __align__(16) short hlds[4][16][40];   // per-wave h tile: 5120 B

  const int tid   = threadIdx.x;
  const int w     = tid >> 6;
  const int lane  = tid & 63;
  const int q     = lane >> 4;       // k-octet role 0..3
  const int c0    = lane & 15;       // A-frag row / B-frag col
  const int cell0 = blockIdx.x << 6;
  const int mycell = cell0 + (w << 4) + c0;

  // ---- ka weights (k = 0..31: window + feat[0:8]) into registers ----
  short8 Wka[8];
  #pragma unroll
  for (int nt = 0; nt < 8; ++nt)
    Wka[nt] = *(const short8*)(wfrag + (nt * 64 + lane) * 8);

  // W_out in permuted (adjacent) order
  const float woutr0 = W_out[2 * c0];
  const float woutr1 = W_out[2 * c0 + 1];
  const float bo = b_out[0];

  // ---- zero this wave's h tile (wave-private, no barrier needed) ----
  {
    short* hz = &hlds[w][0][0];
    for (int i = lane; i < 16 * 40; i += 64) hz[i] = 0;
  }

  const int bb = mycell / CNN, cc = mycell % CNN;

  // register-resident xn window: lane (q<3) holds X[k = q*8 .. q*8+7]
  int wv[4] = {0, 0, 0, 0};
  if (q < 3) {
    const float* src = pm25 + bb * PMROW + cc * HISTN + (q << 3);
    short tmp[8];
    #pragma unroll
    for (int j = 0; j < 8; ++j) tmp[j] = f2bf(src[j]);
    #pragma unroll
    for (int i = 0; i < 4; ++i)
      wv[i] = (int)(((unsigned)(unsigned short)tmp[2 * i]) |
                    (((unsigned)(unsigned short)tmp[2 * i + 1]) << 16));
  }

  // feat prefetch roles: q3 -> feat[0:8] (ka), q0 -> feat[8:16] (kb octet0),
  // q1 -> feat[16] + constant 1.0 bias col (kb octet1), q2 -> none
  const int pfo = (q == 3) ? 0 : (q == 0) ? 8 : 16;
  const float* fptr = feat + (size_t)(bb * 48 + HISTN) * FROW + cc * FN + pfo;
  float pf[8];
  #pragma unroll
  for (int i = 0; i < 8; ++i) pf[i] = 0.f;
  if (q == 1) { pf[0] = fptr[0]; pf[1] = 1.0f; }
  else if (q != 2) {
    #pragma unroll
    for (int i = 0; i < 8; ++i) pf[i] = fptr[i];
  }
  int ci[4];
  #pragma unroll
  for (int i = 0; i < 4; ++i) ci[i] = cvt_pk_bf16(pf[2 * i], pf[2 * i + 1]);

  // output addressing for the 4 D-rows this lane covers (c0==0 stores)
  int obase[4];
  #pragma unroll
  for (int r = 0; r < 4; ++r) {
    const int cgr = cell0 + (w << 4) + (q << 2) + r;
    obase[r] = (cgr / CNN) * (PREDN * CNN) + (cgr % CNN);
  }

  float cst0[4] = {0.f, 0.f, 0.f, 0.f};
  float cst1[4] = {0.f, 0.f, 0.f, 0.f};

  const char* wkb = (const char*)wfrag + 8192;   // f=1 block (kb), f=2 at +8192
  int wofs = lane * 16;                          // per-lane byte offset
  const short* hrd = &hlds[w][c0][q << 3];       // kc A-frag source

  union WU { int i[4]; short8 v8; };

  #pragma unroll 1
  for (int t = 0; t < PREDN; ++t) {
    asm volatile("" : "+v"(wofs));   // keep per-step weight loads in-loop

    // ---- build A-frags (cndmask selects, no divergent convert blocks) ----
    WU au, bu;
    #pragma unroll
    for (int i = 0; i < 4; ++i) au.i[i] = (q == 3) ? ci[i] : wv[i];
    bu.i[0] = (q < 2)  ? ci[0] : 0;
    bu.i[1] = (q == 0) ? ci[1] : 0;
    bu.i[2] = (q == 0) ? ci[2] : 0;
    bu.i[3] = (q == 0) ? ci[3] : 0;
    const short8 ka = au.v8;
    const short8 kb = bu.v8;
    const short8 kc = *(const short8*)hrd;       // h_{t-1}, A-layout

    // ---- issue next-step feature loads (consumed after epilogue) ----
    const bool pfv = (t < PREDN - 1);
    if (pfv) {
      fptr += FROW;
      if (q == 1) pf[0] = fptr[0];
      else if (q != 2) {
        #pragma unroll
        for (int i = 0; i < 8; ++i) pf[i] = fptr[i];
      }
    }

    // ---- gate GEMM, K=96; kb/kc weights streamed from global (L1-hot) ----
    __builtin_amdgcn_s_setprio(1);
    const float4v z4 = {0.f, 0.f, 0.f, 0.f};
    float4v acc[8];
    #pragma unroll
    for (int nt = 0; nt < 8; ++nt) {
      float4v a = MFMA_B16(ka, Wka[nt], z4);
      const short8 wb = *(const short8*)(wkb + wofs + nt * 1024);
      a = MFMA_B16(kb, wb, a);
      const short8 wc = *(const short8*)(wkb + 8192 + wofs + nt * 1024);
      a = MFMA_B16(kc, wc, a);
      acc[nt] = a;
    }
    __builtin_amdgcn_s_setprio(0);

    // ---- epilogue: paired-rcp activations, state update, packed h store ----
    // acc[tau*2 + p][r] = gate tau, hidden j = 2*c0 + p  (permuted layout)
    float part[4] = {0.f, 0.f, 0.f, 0.f};
    #pragma unroll
    for (int r = 0; r < 4; ++r) {
      const float ei0 = X2(-acc[0][r]), ei1 = X2(-acc[1][r]);
      const float ef0 = X2(-acc[2][r]), ef1 = X2(-acc[3][r]);
      const float eg0 = X2( acc[4][r]), eg1 = X2( acc[5][r]);  // 2x pre-scaled
      const float eo0 = X2(-acc[6][r]), eo1 = X2(-acc[7][r]);
      float si0, sf0, si1, sf1, rg0, so0, rg1, so1;
      rcp_pair(ei0, ef0, si0, sf0);
      rcp_pair(ei1, ef1, si1, sf1);
      rcp_pair(eg0, eo0, rg0, so0);
      rcp_pair(eg1, eo1, rg1, so1);
      const float tg0 = fmaf(-2.f, rg0, 1.f);
      const float tg1 = fmaf(-2.f, rg1, 1.f);
      const float cn0 = fmaf(sf0, cst0[r], si0 * tg0);
      const float cn1 = fmaf(sf1, cst1[r], si1 * tg1);
      cst0[r] = cn0; cst1[r] = cn1;
      const float ec0 = X2(cn0 * (2.f * LOG2E));
      const float ec1 = X2(cn1 * (2.f * LOG2E));
      float rc0, rc1;
      rcp_pair(ec0, ec1, rc0, rc1);
      const float h0 = so0 * fmaf(-2.f, rc0, 1.f);
      const float h1 = so1 * fmaf(-2.f, rc1, 1.f);
      *(int*)&hlds[w][(q << 2) + r][c0 << 1] = cvt_pk_bf16(h0, h1);
      part[r] = fmaf(woutr0, h0, part[r]);
      part[r] = fmaf(woutr1, h1, part[r]);
    }

    // ---- convert prefetched feats (loads have had GEMM+epilogue to land) ----
    if (pfv) {
      #pragma unroll
      for (int i = 0; i < 4; ++i) ci[i] = cvt_pk_bf16(pf[2 * i], pf[2 * i + 1]);
    }

    // ---- reduce pred over the 16 lanes of this q-group ----
    #pragma unroll
    for (int r = 0; r < 4; ++r) {
      float p = part[r];
      p += __shfl_xor(p, 1);
      p += __shfl_xor(p, 2);
      p += __shfl_xor(p, 4);
      p += __shfl_xor(p, 8);
      part[r] = p;
    }
    if (c0 == 0) {
      #pragma unroll
      for (int r = 0; r < 4; ++r)
        out[obase[r] + t * CNN] = part[r] + bo;
    }

    // ---- broadcast pred to window-insert lanes, slide the window ----
    if (pfv) {
      const float v01 = (c0 & 1) ? part[1] : part[0];
      const float v23 = (c0 & 1) ? part[3] : part[2];
      const float vs  = (c0 & 2) ? v23 : v01;
      const float pv = __shfl(vs, ((c0 >> 2) << 4) | c0) + bo;
      const int pw = (int)(unsigned short)f2bf(pv);
      const int nb = __shfl(wv[0], (lane + 16) & 63);  // next octet's elem0
      const int inc = (q == 2) ? pw : nb;
      wv[0] = (int)(((unsigned)wv[0] >> 16) | ((unsigned)wv[1] << 16));
      wv[1] = (int)(((unsigned)wv[1] >> 16) | ((unsigned)wv[2] << 16));
      wv[2] = (int)(((unsigned)wv[2] >> 16) | ((unsigned)wv[3] << 16));
      wv[3] = (int)(((unsigned)wv[3] >> 16) | ((unsigned)inc   << 16));
    }
  }
}

extern "C" void kernel_launch(void* const* d_in, const int* in_sizes, int n_in,
                              void* d_out, int out_size, void* d_ws, size_t ws_size,
                              hipStream_t stream) {
  (void)in_sizes; (void)n_in; (void)out_size; (void)ws_size;
  const float* pm25  = (const float*)d_in[0];
  const float* feat  = (const float*)d_in[1];
  // d_in[2] = time_feature, unused by the reference
  const float* W_in  = (const float*)d_in[3];
  const float* b_in  = (const float*)d_in[4];
  const float* W_ih  = (const float*)d_in[5];
  const float* W_hh  = (const float*)d_in[6];
  const float* b_ih  = (const float*)d_in[7];
  const float* b_hh  = (const float*)d_in[8];
  const float* W_out = (const float*)d_in[9];
  const float* b_out = (const float*)d_in[10];
  float* out = (float*)d_out;

  short* wfrag = (short*)d_ws;   // 3 * 8KB = 24576 B of B-frags

  build_weights<<<dim3(6), dim3(256), 0, stream>>>(
      W_in, b_in, W_ih, W_hh, b_ih, b_hh, wfrag);
  lstm_fused<<<dim3(CELLS / 64), dim3(256), 0, stream>>>(
      pm25, feat, wfrag, W_out, b_out, out);
}

// Round 3
// 470.795 us; speedup vs baseline: 1.2095x; 1.2095x over previous
//
#include <hip/hip_runtime.h>

// Fused 24-step LSTM forecaster, MI355X gfx950 — round 3: merge.
//  Round-1's LDS-resident weight frags (fast, off the VMEM critical path)
//  + round-2's VALU diet (folded fc_in, cvt_pk bf16, permuted gate columns,
//  paired reciprocals, native exp2 with pre-scaled weights).
//  LDS = 16KB weights + 5KB h tile; one __syncthreads at start only.

#define BN     512
#define HISTN  24
#define CNN    184
#define FN     17
#define PREDN  24
#define HIDN   32
#define INN    41
#define CELLS  (BN * CNN)          // 94208 cells, 64/block -> 1472 blocks
#define FROW   (CNN * FN)
#define PMROW  (HISTN * CNN)
#define LOG2E  1.4426950408889634f

typedef __attribute__((ext_vector_type(8))) short  short8;
typedef __attribute__((ext_vector_type(4))) float  float4v;
typedef __attribute__((ext_vector_type(4))) int    int4v;

#define MFMA_B16(a,b,c) __builtin_amdgcn_mfma_f32_16x16x32_bf16(a,b,c,0,0,0)
#define X2(x) __builtin_amdgcn_exp2f(x)

__device__ __forceinline__ short f2bf(float f) {
  union { float f; unsigned u; } v; v.f = f;
  unsigned r = v.u + 0x7fffu + ((v.u >> 16) & 1u);   // RNE
  return (short)(r >> 16);
}
__device__ __forceinline__ int cvt_pk_bf16(float lo, float hi) {
  int r;
  asm("v_cvt_pk_bf16_f32 %0, %1, %2" : "=v"(r) : "v"(lo), "v"(hi));
  return r;
}
// ra = 1/(1+ea), rb = 1/(1+eb) with a single v_rcp.
__device__ __forceinline__ void rcp_pair(float ea, float eb, float& ra, float& rb) {
  const float s  = ea + eb;
  const float p  = fmaf(ea, eb, s) + 1.0f;   // (1+ea)(1+eb)
  const float rr = __builtin_amdgcn_rcpf(p);
  ra = fmaf(eb, rr, rr);
  rb = fmaf(ea, rr, rr);
}

// ---------------------------------------------------------------------------
// Setup: folded gate weights (fc_in absorbed, bias as constant-1 column),
// bf16, MFMA B-frag order, PERMUTED gate columns:
//   tile nt = tau*2 + (j&1), col c0 = j>>1   (tau = gate type, j = hidden idx)
// Scale: log2(e) for i,f,o rows; 2*log2(e) for g rows (tanh's 2x folded in).
__global__ void build_weights(const float* __restrict__ W_in, const float* __restrict__ b_in,
                              const float* __restrict__ W_ih, const float* __restrict__ W_hh,
                              const float* __restrict__ b_ih, const float* __restrict__ b_hh,
                              short* __restrict__ wfrag)
{
  const int tid = blockIdx.x * 256 + threadIdx.x;
  if (tid >= 128 * 12) return;
  const int g  = tid / 12;         // source gate row 0..127 (i,f,g,o blocks)
  const int kg = tid % 12;         // k-octet 0..11
  const int k0 = kg * 8;

  float v[8];
  #pragma unroll
  for (int j = 0; j < 8; ++j) v[j] = 0.f;

  if (k0 < INN) {                  // folded fc_in region (k = 0..40)
    for (int m = 0; m < HIDN; ++m) {
      const float wih = W_ih[g * HIDN + m];
      #pragma unroll
      for (int j = 0; j < 8; ++j) {
        const int k = k0 + j;
        if (k < INN) v[j] += wih * W_in[m * INN + k];
      }
    }
  }
  if (k0 <= INN && INN < k0 + 8) { // bias column k = 41
    float bv = b_ih[g] + b_hh[g];
    for (int m = 0; m < HIDN; ++m) bv += W_ih[g * HIDN + m] * b_in[m];
    v[INN - k0] = bv;
  }
  if (k0 >= 64) {                  // W_hh region (k = 64..95)
    #pragma unroll
    for (int j = 0; j < 8; ++j) v[j] = W_hh[g * HIDN + (k0 + j - 64)];
  }

  const int tau = g >> 5;          // 0=i 1=f 2=g 3=o
  const int jj  = g & 31;
  const int nt  = tau * 2 + (jj & 1);
  const int c0  = jj >> 1;
  const int f   = kg >> 2, q = kg & 3;
  const float scale = (tau == 2) ? (2.0f * LOG2E) : LOG2E;
  short* dst = wfrag + (((f * 8 + nt) * 64 + q * 16 + c0) * 8);
  #pragma unroll
  for (int j = 0; j < 8; ++j) dst[j] = f2bf(v[j] * scale);
}

// ---------------------------------------------------------------------------
__global__ __launch_bounds__(256, 4)
void lstm_fused(const float* __restrict__ pm25,
                const float* __restrict__ feat,
                const short* __restrict__ wfrag,
                const float* __restrict__ W_out, const float* __restrict__ b_out,
                float* __restrict__ out)
{
  __shared__ __align__(16) short wlds[2 * 8 * 64 * 8];   // kb,kc weight frags: 16 KB
  __shared__ __align__(16) short hlds[4][16][40];        // per-wave h tile: 5120 B

  const int tid   = threadIdx.x;
  const int w     = tid >> 6;
  const int lane  = tid & 63;
  const int q     = lane >> 4;       // k-octet role 0..3
  const int c0    = lane & 15;       // A-frag row / B-frag col
  const int cell0 = blockIdx.x << 6;
  const int mycell = cell0 + (w << 4) + c0;

  // ---- stage kb/kc weight frags to LDS (16384 B, coalesced) ----
  {
    const int4v* src = (const int4v*)(wfrag + 8 * 64 * 8);   // skip ka block
    int4v* dst = (int4v*)wlds;
    #pragma unroll
    for (int i = 0; i < 4; ++i) dst[tid + 256 * i] = src[tid + 256 * i];
  }

  // ---- ka weights (k = 0..31: window + feat[0:8]) into registers ----
  short8 Wka[8];
  #pragma unroll
  for (int nt = 0; nt < 8; ++nt)
    Wka[nt] = *(const short8*)(wfrag + (nt * 64 + lane) * 8);

  // W_out in permuted (adjacent) order
  const float woutr0 = W_out[2 * c0];
  const float woutr1 = W_out[2 * c0 + 1];
  const float bo = b_out[0];

  // ---- zero this wave's h tile ----
  {
    short* hz = &hlds[w][0][0];
    for (int i = lane; i < 16 * 40; i += 64) hz[i] = 0;
  }

  const int bb = mycell / CNN, cc = mycell % CNN;

  // register-resident xn window: lane (q<3) holds X[k = q*8 .. q*8+7]
  int wv[4] = {0, 0, 0, 0};
  if (q < 3) {
    const float* src = pm25 + bb * PMROW + cc * HISTN + (q << 3);
    short tmp[8];
    #pragma unroll
    for (int j = 0; j < 8; ++j) tmp[j] = f2bf(src[j]);
    #pragma unroll
    for (int i = 0; i < 4; ++i)
      wv[i] = (int)(((unsigned)(unsigned short)tmp[2 * i]) |
                    (((unsigned)(unsigned short)tmp[2 * i + 1]) << 16));
  }

  // feat prefetch roles: q3 -> feat[0:8] (ka), q0 -> feat[8:16] (kb octet0),
  // q1 -> feat[16] + constant 1.0 bias col (kb octet1), q2 -> none
  const int pfo = (q == 3) ? 0 : (q == 0) ? 8 : 16;
  const float* fptr = feat + (size_t)(bb * 48 + HISTN) * FROW + cc * FN + pfo;
  float pf[8];
  #pragma unroll
  for (int i = 0; i < 8; ++i) pf[i] = 0.f;
  if (q == 1) { pf[0] = fptr[0]; pf[1] = 1.0f; }
  else if (q != 2) {
    #pragma unroll
    for (int i = 0; i < 8; ++i) pf[i] = fptr[i];
  }
  int ci[4];
  #pragma unroll
  for (int i = 0; i < 4; ++i) ci[i] = cvt_pk_bf16(pf[2 * i], pf[2 * i + 1]);

  // output addressing for the 4 D-rows this lane covers (c0==0 stores)
  int obase[4];
  #pragma unroll
  for (int r = 0; r < 4; ++r) {
    const int cgr = cell0 + (w << 4) + (q << 2) + r;
    obase[r] = (cgr / CNN) * (PREDN * CNN) + (cgr % CNN);
  }

  float cst0[4] = {0.f, 0.f, 0.f, 0.f};
  float cst1[4] = {0.f, 0.f, 0.f, 0.f};

  __syncthreads();   // wlds staged

  const char* wl = (const char*)wlds;
  int wofs = lane * 16;                          // per-lane byte offset
  const short* hrd = &hlds[w][c0][q << 3];       // kc A-frag source

  union WU { int i[4]; short8 v8; };

  #pragma unroll 1
  for (int t = 0; t < PREDN; ++t) {
    asm volatile("" : "+v"(wofs));   // keep per-step LDS weight reads in-loop

    // ---- build A-frags (cndmask selects) ----
    WU au, bu;
    #pragma unroll
    for (int i = 0; i < 4; ++i) au.i[i] = (q == 3) ? ci[i] : wv[i];
    bu.i[0] = (q < 2)  ? ci[0] : 0;
    bu.i[1] = (q == 0) ? ci[1] : 0;
    bu.i[2] = (q == 0) ? ci[2] : 0;
    bu.i[3] = (q == 0) ? ci[3] : 0;
    const short8 ka = au.v8;
    const short8 kb = bu.v8;
    const short8 kc = *(const short8*)hrd;       // h_{t-1}, A-layout

    // ---- issue next-step feature loads (consumed after epilogue) ----
    const bool pfv = (t < PREDN - 1);
    if (pfv) {
      fptr += FROW;
      if (q == 1) pf[0] = fptr[0];
      else if (q != 2) {
        #pragma unroll
        for (int i = 0; i < 8; ++i) pf[i] = fptr[i];
      }
    }

    // ---- gate GEMM, K=96; kb/kc weights from LDS ----
    __builtin_amdgcn_s_setprio(1);
    const float4v z4 = {0.f, 0.f, 0.f, 0.f};
    float4v acc[8];
    #pragma unroll
    for (int nt = 0; nt < 8; ++nt) {
      float4v a = MFMA_B16(ka, Wka[nt], z4);
      const short8 wb = *(const short8*)(wl + wofs + nt * 1024);
      a = MFMA_B16(kb, wb, a);
      const short8 wc = *(const short8*)(wl + 8192 + wofs + nt * 1024);
      a = MFMA_B16(kc, wc, a);
      acc[nt] = a;
    }
    __builtin_amdgcn_s_setprio(0);

    // ---- epilogue: paired-rcp activations, state update, packed h store ----
    // acc[tau*2 + p][r] = gate tau, hidden j = 2*c0 + p  (permuted layout)
    float part[4] = {0.f, 0.f, 0.f, 0.f};
    #pragma unroll
    for (int r = 0; r < 4; ++r) {
      const float ei0 = X2(-acc[0][r]), ei1 = X2(-acc[1][r]);
      const float ef0 = X2(-acc[2][r]), ef1 = X2(-acc[3][r]);
      const float eg0 = X2( acc[4][r]), eg1 = X2( acc[5][r]);  // 2x pre-scaled
      const float eo0 = X2(-acc[6][r]), eo1 = X2(-acc[7][r]);
      float si0, sf0, si1, sf1, rg0, so0, rg1, so1;
      rcp_pair(ei0, ef0, si0, sf0);
      rcp_pair(ei1, ef1, si1, sf1);
      rcp_pair(eg0, eo0, rg0, so0);
      rcp_pair(eg1, eo1, rg1, so1);
      const float tg0 = fmaf(-2.f, rg0, 1.f);
      const float tg1 = fmaf(-2.f, rg1, 1.f);
      const float cn0 = fmaf(sf0, cst0[r], si0 * tg0);
      const float cn1 = fmaf(sf1, cst1[r], si1 * tg1);
      cst0[r] = cn0; cst1[r] = cn1;
      const float ec0 = X2(cn0 * (2.f * LOG2E));
      const float ec1 = X2(cn1 * (2.f * LOG2E));
      float rc0, rc1;
      rcp_pair(ec0, ec1, rc0, rc1);
      const float h0 = so0 * fmaf(-2.f, rc0, 1.f);
      const float h1 = so1 * fmaf(-2.f, rc1, 1.f);
      *(int*)&hlds[w][(q << 2) + r][c0 << 1] = cvt_pk_bf16(h0, h1);
      part[r] = fmaf(woutr0, h0, part[r]);
      part[r] = fmaf(woutr1, h1, part[r]);
    }

    // ---- convert prefetched feats (loads had GEMM+epilogue to land) ----
    if (pfv) {
      #pragma unroll
      for (int i = 0; i < 4; ++i) ci[i] = cvt_pk_bf16(pf[2 * i], pf[2 * i + 1]);
    }

    // ---- reduce pred over the 16 lanes of this q-group ----
    #pragma unroll
    for (int r = 0; r < 4; ++r) {
      float p = part[r];
      p += __shfl_xor(p, 1);
      p += __shfl_xor(p, 2);
      p += __shfl_xor(p, 4);
      p += __shfl_xor(p, 8);
      part[r] = p;
    }
    if (c0 == 0) {
      #pragma unroll
      for (int r = 0; r < 4; ++r)
        out[obase[r] + t * CNN] = part[r] + bo;
    }

    // ---- broadcast pred to window-insert lanes, slide the window ----
    if (pfv) {
      const float v01 = (c0 & 1) ? part[1] : part[0];
      const float v23 = (c0 & 1) ? part[3] : part[2];
      const float vs  = (c0 & 2) ? v23 : v01;
      const float pv = __shfl(vs, ((c0 >> 2) << 4) | c0) + bo;
      const int cp = cvt_pk_bf16(pv, pv);              // low half = bf16(pv)
      const int nb = __shfl(wv[0], (lane + 16) & 63);  // next octet's elem0
      const int inc = (q == 2) ? cp : nb;
      wv[0] = (int)(((unsigned)wv[0] >> 16) | ((unsigned)wv[1] << 16));
      wv[1] = (int)(((unsigned)wv[1] >> 16) | ((unsigned)wv[2] << 16));
      wv[2] = (int)(((unsigned)wv[2] >> 16) | ((unsigned)wv[3] << 16));
      wv[3] = (int)(((unsigned)wv[3] >> 16) | ((unsigned)inc   << 16));
    }
  }
}

extern "C" void kernel_launch(void* const* d_in, const int* in_sizes, int n_in,
                              void* d_out, int out_size, void* d_ws, size_t ws_size,
                              hipStream_t stream) {
  (void)in_sizes; (void)n_in; (void)out_size; (void)ws_size;
  const float* pm25  = (const float*)d_in[0];
  const float* feat  = (const float*)d_in[1];
  // d_in[2] = time_feature, unused by the reference
  const float* W_in  = (const float*)d_in[3];
  const float* b_in  = (const float*)d_in[4];
  const float* W_ih  = (const float*)d_in[5];
  const float* W_hh  = (const float*)d_in[6];
  const float* b_ih  = (const float*)d_in[7];
  const float* b_hh  = (const float*)d_in[8];
  const float* W_out = (const float*)d_in[9];
  const float* b_out = (const float*)d_in[10];
  float* out = (float*)d_out;

  short* wfrag = (short*)d_ws;   // 3 * 8KB of B-frags

  build_weights<<<dim3(6), dim3(256), 0, stream>>>(
      W_in, b_in, W_ih, W_hh, b_ih, b_hh, wfrag);
  lstm_fused<<<dim3(CELLS / 64), dim3(256), 0, stream>>>(
      pm25, feat, wfrag, W_out, b_out, out);
}